// Round 9
// baseline (36.056 us; speedup 1.0000x reference)
//
#include <hip/hip_runtime.h>
#include <hip/hip_bf16.h>
#include <math.h>

#define TAGS   20
#define TSTART (TAGS - 2)
#define TSTOP  (TAGS - 1)

constexpr float  LOG2E = 1.4426950408889634f;
constexpr float  LN2f  = 0.6931471805599453f;
constexpr double LN2d  = 0.69314718055994530942;

typedef __attribute__((ext_vector_type(8))) short short8;
typedef __attribute__((ext_vector_type(4))) float f32x4;
union U4 { unsigned int u[4]; short8 v; };

// f32x2 -> packed bf16x2, round-half-up (+0x8000 then high halves via one
// v_perm_b32) — validated rounds 7/8, absmax 0.0. 3 VALU ops.
__device__ __forceinline__ unsigned int pk2(float lo, float hi) {
    unsigned int a = __float_as_uint(hi) + 0x8000u;
    unsigned int b = __float_as_uint(lo) + 0x8000u;
#if __has_builtin(__builtin_amdgcn_perm)
    return __builtin_amdgcn_perm(a, b, 0x07060302u);   // {a[31:16], b[31:16]}
#else
    return (a & 0xFFFF0000u) | (b >> 16);
#endif
}
#if __has_builtin(__builtin_amdgcn_exp2f)
__device__ __forceinline__ float fexp2(float x) { return __builtin_amdgcn_exp2f(x); }
#else
__device__ __forceinline__ float fexp2(float x) { return exp2f(x); }
#endif
#if __has_builtin(__builtin_amdgcn_logf)
__device__ __forceinline__ float flog2(float x) { return __builtin_amdgcn_logf(x); }
#else
__device__ __forceinline__ float flog2(float x) { return log2f(x); }
#endif
__device__ __forceinline__ float frcp(float x) { return __builtin_amdgcn_rcpf(x); }
__device__ __forceinline__ float bcast(float v, int srclane) {
    return __int_as_float(__builtin_amdgcn_readlane(__float_as_int(v), srclane));
}
// k-slot -> state-row permutation (split-half layout of gfx950 16x16x32),
// applied consistently to A and B (validated end-to-end: rounds 4/5/7/8).
__device__ __forceinline__ int rho(int k) {
    int g = k >> 3, i = k & 7;
    return (i < 4) ? (4 * g + i) : (16 + 4 * g + (i - 4));
}

// ========================== FUSED KERNEL ==================================
// One block = one batch. 8 waves; wave w owns chunks w and w+8 (32 steps
// each, interleaved for ILP). A-side scaling: per step the emission diag AND
// the pending renorm scale are folded into the A operand (independent of C,
// built while MFMAs are in flight); B = pk2(raw C) -> critical chain is just
// pack->MFMA. Exponent strip measured every step, applied via the next A;
// final pending s applied explicitly. Then a 4-level MFMA tree in LDS,
// final v0^T*G, LSE, gold.
__global__ __launch_bounds__(512)
void crf_fused_kernel(const float* __restrict__ feats,
                      const float* __restrict__ Tm,
                      const int*   __restrict__ tags,
                      const int*   __restrict__ lengths,
                      double*      __restrict__ partial,
                      int L)
{
    __shared__ float  smem[16 * 1024];   // 64 KB: ef staging; later tree slots (stride 1088)
    __shared__ float  sv[32];
    __shared__ int    EsX[8];
    __shared__ float  gred[8];
    __shared__ double fwd_sh;

    const int b    = blockIdx.x;
    const int tid  = threadIdx.x;
    const int w    = tid >> 6;
    const int lane = tid & 63;
    const int G    = lane >> 4, col = lane & 15;
    const int len  = lengths[b];

    // ---- stage ef = 2^(feat*log2e) for chunks w and w+8 (32x32, pads 0) ----
    #pragma unroll
    for (int s = 0; s < 2; ++s) {
        const int c = w + 8 * s;
        float* efc = smem + c * 1024;
        const float* fc = feats + ((size_t)b * L + (size_t)c * 32) * TAGS;
        for (int it = lane; it < 160; it += 64) {       // 160 float4 = 640 floats
            float4 v = reinterpret_cast<const float4*>(fc)[it];
            float vv[4] = {v.x, v.y, v.z, v.w};
            #pragma unroll
            for (int u = 0; u < 4; ++u) {
                int f = it * 4 + u;
                int t = f / TAGS, tag = f - t * TAGS;
                efc[t * 32 + tag] = fexp2(vv[u] * LOG2E);
            }
        }
        for (int q = lane; q < 32 * 12; q += 64) {
            int t = q / 12;
            efc[t * 32 + 20 + (q - t * 12)] = 0.f;
        }
    }
    __syncthreads();

    // ---- ET in f32 registers: ET0[e] = 2^(T[col][rho(8G+e)]*log2e),
    //      ET1[e] same with m = 16+col; pads 0 ----
    float ET0[8], ET1[8];
    #pragma unroll
    for (int e = 0; e < 8; ++e) {
        int r  = rho(8 * G + e);
        int m1 = 16 + col;
        ET0[e] = (r < TAGS) ? fexp2(Tm[col * TAGS + r] * LOG2E) : 0.f;
        ET1[e] = (m1 < TAGS && r < TAGS) ? fexp2(Tm[m1 * TAGS + r] * LOG2E) : 0.f;
    }

    // step: C <- (s * ET * D_l) * C ; measure exponent, fold into next s.
    auto step = [&](f32x4& C00, f32x4& C01, f32x4& C10, f32x4& C11,
                    float& s, int& E, const float* efc, int t) {
        float4 e0 = *reinterpret_cast<const float4*>(&efc[t * 32 + 4 * G]);
        float4 e1 = *reinterpret_cast<const float4*>(&efc[t * 32 + 16 + 4 * G]);
        // off-critical-path: scaled emission + A build (depends on s, ef only)
        float f0 = s * e0.x, f1 = s * e0.y, f2 = s * e0.z, f3 = s * e0.w;
        float f4 = s * e1.x, f5 = s * e1.y, f6 = s * e1.z, f7 = s * e1.w;
        U4 Al0, Al1;
        Al0.u[0] = pk2(ET0[0] * f0, ET0[1] * f1);
        Al0.u[1] = pk2(ET0[2] * f2, ET0[3] * f3);
        Al0.u[2] = pk2(ET0[4] * f4, ET0[5] * f5);
        Al0.u[3] = pk2(ET0[6] * f6, ET0[7] * f7);
        Al1.u[0] = pk2(ET1[0] * f0, ET1[1] * f1);
        Al1.u[1] = pk2(ET1[2] * f2, ET1[3] * f3);
        Al1.u[2] = pk2(ET1[4] * f4, ET1[5] * f5);
        Al1.u[3] = pk2(ET1[6] * f6, ET1[7] * f7);
        // critical path: pack raw C -> MFMA
        U4 B0, B1;
        B0.u[0] = pk2(C00[0], C00[1]);
        B0.u[1] = pk2(C00[2], C00[3]);
        B0.u[2] = pk2(C10[0], C10[1]);
        B0.u[3] = pk2(C10[2], C10[3]);
        B1.u[0] = pk2(C01[0], C01[1]);
        B1.u[1] = pk2(C01[2], C01[3]);
        B1.u[2] = pk2(C11[0], C11[1]);
        B1.u[3] = pk2(C11[2], C11[3]);
        f32x4 z = {0.f, 0.f, 0.f, 0.f};
        C00 = __builtin_amdgcn_mfma_f32_16x16x32_bf16(Al0.v, B0.v, z, 0, 0, 0);
        C01 = __builtin_amdgcn_mfma_f32_16x16x32_bf16(Al0.v, B1.v, z, 0, 0, 0);
        C10 = __builtin_amdgcn_mfma_f32_16x16x32_bf16(Al1.v, B0.v, z, 0, 0, 0);
        C11 = __builtin_amdgcn_mfma_f32_16x16x32_bf16(Al1.v, B1.v, z, 0, 0, 0);
        // exponent strip (measure now, apply via NEXT step's A)
        float pr = C00[0] + C00[1] + C00[2] + C00[3] + C10[0] + C10[1] + C10[2] + C10[3];
        int pb = __builtin_amdgcn_readfirstlane(__float_as_int(pr)); // col0 sum, >0 always
        int ex = ((pb >> 23) & 0xFF) - 127;
        s = __uint_as_float((unsigned)(127 - ex) << 23);             // 2^-ex
        E += ex;
    };

    auto strip = [&](f32x4& C00, f32x4& C01, f32x4& C10, f32x4& C11) -> int {
        float pr = C00[0] + C00[1] + C00[2] + C00[3] + C10[0] + C10[1] + C10[2] + C10[3];
        int pb = __builtin_amdgcn_readfirstlane(__float_as_int(pr));
        int ex = ((pb >> 23) & 0xFF) - 127;
        float s = __uint_as_float((unsigned)(127 - ex) << 23);
        #pragma unroll
        for (int j = 0; j < 4; ++j) { C00[j] *= s; C01[j] *= s; C10[j] *= s; C11[j] *= s; }
        return ex;
    };
    auto xwr = [&](int slot, const f32x4& C00, const f32x4& C01,
                   const f32x4& C10, const f32x4& C11, int E) {
        float* Xs = smem + slot * 1088;                 // row-major, stride 34
        #pragma unroll
        for (int j = 0; j < 4; ++j) {
            Xs[(4 * G + j) * 34 + col]           = C00[j];
            Xs[(4 * G + j) * 34 + col + 16]      = C01[j];
            Xs[(16 + 4 * G + j) * 34 + col]      = C10[j];
            Xs[(16 + 4 * G + j) * 34 + col + 16] = C11[j];
        }
        if (lane == 0) EsX[slot] = E;
    };
    auto prod = [&](int slot, f32x4& C00, f32x4& C01, f32x4& C10, f32x4& C11) -> int {
        const float* Xs = smem + slot * 1088;
        U4 Ax0, Ax1;
        #pragma unroll
        for (int t = 0; t < 4; ++t) {
            int r = rho(8 * G + 2 * t);                 // rho(k0), rho(k0+1) adjacent
            float2 x0 = *reinterpret_cast<const float2*>(&Xs[col * 34 + r]);
            float2 x1 = *reinterpret_cast<const float2*>(&Xs[(16 + col) * 34 + r]);
            Ax0.u[t] = pk2(x0.x, x0.y);
            Ax1.u[t] = pk2(x1.x, x1.y);
        }
        U4 B0, B1;
        B0.u[0] = pk2(C00[0], C00[1]);
        B0.u[1] = pk2(C00[2], C00[3]);
        B0.u[2] = pk2(C10[0], C10[1]);
        B0.u[3] = pk2(C10[2], C10[3]);
        B1.u[0] = pk2(C01[0], C01[1]);
        B1.u[1] = pk2(C01[2], C01[3]);
        B1.u[2] = pk2(C11[0], C11[1]);
        B1.u[3] = pk2(C11[2], C11[3]);
        f32x4 z = {0.f, 0.f, 0.f, 0.f};
        f32x4 n00 = __builtin_amdgcn_mfma_f32_16x16x32_bf16(Ax0.v, B0.v, z, 0, 0, 0);
        f32x4 n01 = __builtin_amdgcn_mfma_f32_16x16x32_bf16(Ax0.v, B1.v, z, 0, 0, 0);
        f32x4 n10 = __builtin_amdgcn_mfma_f32_16x16x32_bf16(Ax1.v, B0.v, z, 0, 0, 0);
        f32x4 n11 = __builtin_amdgcn_mfma_f32_16x16x32_bf16(Ax1.v, B1.v, z, 0, 0, 0);
        C00 = n00; C01 = n01; C10 = n10; C11 = n11;
        return strip(C00, C01, C10, C11);
    };

    // ---- two interleaved 32-step chunk products (chains: chunk w, chunk w+8) ----
    f32x4 aC00, aC01, aC10, aC11, bC00, bC01, bC10, bC11;
    #pragma unroll
    for (int j = 0; j < 4; ++j) {
        float d = (4 * G + j == col) ? 1.f : 0.f;       // R = I (pad diag harmless)
        aC00[j] = d; aC11[j] = d; aC01[j] = 0.f; aC10[j] = 0.f;
        bC00[j] = d; bC11[j] = d; bC01[j] = 0.f; bC10[j] = 0.f;
    }
    int   aE = 0,   bE = 0;
    float sA = 1.f, sB = 1.f;

    const int cB  = w + 8;
    const int loA = (w == 0) ? 1 : w * 32;
    const int hiA = min(w * 32 + 31, len - 1);
    const int loB = cB * 32;
    const int hiB = min(cB * 32 + 31, len - 1);
    int nA = hiA - loA + 1; if (nA < 0) nA = 0;
    int nB = hiB - loB + 1; if (nB < 0) nB = 0;
    const int n = max(nA, nB);
    const float* efA = smem + w * 1024;
    const float* efB = smem + cB * 1024;

    int lA = hiA, lB = hiB;
    for (int i = 0; i < n; ++i) {
        if (i < nA) { step(aC00, aC01, aC10, aC11, sA, aE, efA, lA - w * 32);  --lA; }
        if (i < nB) { step(bC00, bC01, bC10, bC11, sB, bE, efB, lB - cB * 32); --lB; }
    }
    // apply the final pending renorm scale (its ex is already in E)
    #pragma unroll
    for (int j = 0; j < 4; ++j) {
        aC00[j] *= sA; aC01[j] *= sA; aC10[j] *= sA; aC11[j] *= sA;
        bC00[j] *= sB; bC01[j] *= sB; bC10[j] *= sB; bC11[j] *= sB;
    }
    __syncthreads();   // ef region dead; reuse smem as tree slots

    // ---- tree level 1: P_p = G_{2p} * G_{2p+1} ----
    if ((w & 1) == 0) {
        xwr(w / 2,     aC00, aC01, aC10, aC11, aE);
        xwr(w / 2 + 4, bC00, bC01, bC10, bC11, bE);
    }
    __syncthreads();
    if (w & 1) {
        int pA = (w - 1) / 2;
        aE += EsX[pA]     + prod(pA,     aC00, aC01, aC10, aC11);
        bE += EsX[pA + 4] + prod(pA + 4, bC00, bC01, bC10, bC11);
    }
    __syncthreads();
    // ---- level 2: Q_q = P_{2q} * P_{2q+1} ----
    if (w == 1 || w == 5) {
        xwr((w - 1) / 4,     aC00, aC01, aC10, aC11, aE);
        xwr((w - 1) / 4 + 2, bC00, bC01, bC10, bC11, bE);
    }
    __syncthreads();
    if (w == 3 || w == 7) {
        int q = (w - 3) / 4;
        aE += EsX[q]     + prod(q,     aC00, aC01, aC10, aC11);
        bE += EsX[q + 2] + prod(q + 2, bC00, bC01, bC10, bC11);
    }
    __syncthreads();
    // ---- level 3: R_r = Q_{2r} * Q_{2r+1} ----
    if (w == 3) {
        xwr(0, aC00, aC01, aC10, aC11, aE);
        xwr(1, bC00, bC01, bC10, bC11, bE);
    }
    __syncthreads();
    if (w == 7) {
        aE += EsX[0] + prod(0, aC00, aC01, aC10, aC11);
        bE += EsX[1] + prod(1, bC00, bC01, bC10, bC11);
    }
    __syncthreads();
    // ---- level 4 (same wave: no barrier needed between write & read) ----
    if (w == 7) {
        xwr(0, aC00, aC01, aC10, aC11, aE);
        int ex = prod(0, bC00, bC01, bC10, bC11);    // G_total = R_0 * R_1
        int fE = aE + bE + ex;
        float* Gt = smem;                             // col-major: Gt[n*34 + r]
        #pragma unroll
        for (int j = 0; j < 4; ++j) {
            Gt[col * 34 + 4 * G + j]            = bC00[j];
            Gt[col * 34 + 16 + 4 * G + j]       = bC10[j];
            Gt[(col + 16) * 34 + 4 * G + j]     = bC01[j];
            Gt[(col + 16) * 34 + 16 + 4 * G + j]= bC11[j];
        }
        if (lane == 0) EsX[0] = fE;
    }
    __syncthreads();

    // ---- final: part^T = v0^T G_total ; LSE with T[:,STOP] (max-subtracted;
    //      the STOP column is -10000 everywhere!) ----
    if (w == 0) {
        const int n2 = lane & 31;
        float p = (n2 < TAGS) ? (feats[(size_t)b * L * TAGS + n2] + Tm[TSTART * TAGS + n2]) * LOG2E
                              : -1e30f;
        float mx = p;
        #pragma unroll
        for (int off = 32; off; off >>= 1) mx = fmaxf(mx, __shfl_xor(mx, off));
        float v = (n2 < TAGS) ? fexp2(p - mx) : 0.f;
        if (lane < 32) sv[lane] = v;                  // same-wave DS ordering
        const float* Gt = smem;
        float vn = 0.f;
        #pragma unroll
        for (int r = 0; r < 32; r += 2) {
            float2 g2 = *reinterpret_cast<const float2*>(&Gt[n2 * 34 + r]);
            vn = fmaf(sv[r], g2.x, vn);
            vn = fmaf(sv[r + 1], g2.y, vn);
        }
        float cstop = Tm[n2 * TAGS + TSTOP];
        float mc = (n2 < TAGS) ? cstop : -INFINITY;
        #pragma unroll
        for (int off = 32; off; off >>= 1) mc = fmaxf(mc, __shfl_xor(mc, off));
        float ts = (lane < 32 && n2 < TAGS) ? vn * fexp2((cstop - mc) * LOG2E) : 0.f;
        #pragma unroll
        for (int off = 32; off; off >>= 1) ts += __shfl_xor(ts, off);
        if (lane == 0)
            fwd_sh = ((double)mx + (double)EsX[0] + (double)flog2(ts)) * LN2d + (double)mc;
    }

    // ---- gold path score (all 512 threads) ----
    float g = 0.f;
    for (int l = tid; l < len; l += 512) {
        int tt = tags[(size_t)b * L + l];
        int pv = (l == 0) ? TSTART : tags[(size_t)b * L + l - 1];
        g += feats[((size_t)b * L + l) * TAGS + tt] + Tm[pv * TAGS + tt];
    }
    #pragma unroll
    for (int off = 32; off; off >>= 1) g += __shfl_xor(g, off);
    if (lane == 0) gred[w] = g;
    __syncthreads();

    if (tid == 0) {
        float gs = gred[0] + gred[1] + gred[2] + gred[3]
                 + gred[4] + gred[5] + gred[6] + gred[7];
        double gold = (double)gs + (double)Tm[tags[(size_t)b * L + len - 1] * TAGS + TSTOP];
        partial[b] = fwd_sh - gold;
    }
}

// ==================== FALLBACK (round-2 serial kernel) ====================
__global__ __launch_bounds__(64)
void crf_fwd_kernel(const float* __restrict__ feats,
                    const float* __restrict__ Tm,
                    const int*   __restrict__ tags,
                    const int*   __restrict__ lengths,
                    double*      __restrict__ partial,
                    int B, int L)
{
    __shared__ float le[512 * TAGS];
    const int b    = blockIdx.x;
    const int lane = threadIdx.x;
    const int j    = (lane < TAGS) ? lane : 0;
    const float* fb  = feats + (size_t)b * L * TAGS;
    const int*   tg  = tags  + (size_t)b * L;
    const int    len = lengths[b];

    const int nv4 = (L * TAGS) >> 2;
    for (int it = lane; it < nv4; it += 64) {
        float4 v = reinterpret_cast<const float4*>(fb)[it];
        float4 e;
        e.x = fexp2(v.x * LOG2E); e.y = fexp2(v.y * LOG2E);
        e.z = fexp2(v.z * LOG2E); e.w = fexp2(v.w * LOG2E);
        reinterpret_cast<float4*>(le)[it] = e;
    }
    __syncthreads();

    float ET[TAGS];
    #pragma unroll
    for (int i = 0; i < TAGS; ++i) ET[i] = fexp2(Tm[i * TAGS + j] * LOG2E);

    float w0   = flog2(le[j]) + Tm[TSTART * TAGS + j] * LOG2E;
    float base = bcast(w0, 0);
    float P    = fexp2(w0 - base);
    float M2   = base;
    float Pa[TAGS];
    #pragma unroll
    for (int i = 0; i < TAGS; ++i) Pa[i] = bcast(P, i);
    const float* leb = le + j;

    auto STEP = [&](int l, float efv, float rsv, bool scaled) {
        float s0 = 0.f, s1 = 0.f, s2 = 0.f, s3 = 0.f;
        #pragma unroll
        for (int i = 0; i < TAGS; i += 4) {
            s0 = fmaf(ET[i + 0], Pa[i + 0], s0);
            s1 = fmaf(ET[i + 1], Pa[i + 1], s1);
            s2 = fmaf(ET[i + 2], Pa[i + 2], s2);
            s3 = fmaf(ET[i + 3], Pa[i + 3], s3);
        }
        float s   = (s0 + s1) + (s2 + s3);
        float cur = s * efv;
        float pn  = (l < len) ? cur : P;
        P = scaled ? pn * rsv : pn;
        #pragma unroll
        for (int i = 0; i < TAGS; ++i) Pa[i] = bcast(P, i);
    };

    float efb[4];
    #pragma unroll
    for (int k = 0; k < 4; ++k) { int ln = 1 + k; ln = (ln < L) ? ln : (L - 1); efb[k] = leb[ln * TAGS]; }

    float rs = 1.0f, lg0 = 0.0f;
    int l0 = 1;
    for (; l0 + 3 < L; l0 += 4) {
        if (l0 >= len) break;
        float efn[4];
        #pragma unroll
        for (int k = 0; k < 4; ++k) { int ln = l0 + 4 + k; ln = (ln < L) ? ln : (L - 1); efn[k] = leb[ln * TAGS]; }
        M2 += lg0;
        STEP(l0 + 0, efb[0], rs, true);
        STEP(l0 + 1, efb[1], 1.f, false);
        STEP(l0 + 2, efb[2], 1.f, false);
        STEP(l0 + 3, efb[3], 1.f, false);
        float p0 = Pa[0];
        rs = frcp(p0); lg0 = flog2(p0);
        #pragma unroll
        for (int k = 0; k < 4; ++k) efb[k] = efn[k];
    }
    if (l0 < len) {
        int rem = L - l0;
        M2 += lg0;
        if (rem > 0) STEP(l0 + 0, efb[0], rs, true);
        if (rem > 1) STEP(l0 + 1, efb[1], 1.f, false);
        if (rem > 2) STEP(l0 + 2, efb[2], 1.f, false);
        if (rem > 3) STEP(l0 + 3, efb[3], 1.f, false);
    }

    float cstop = Tm[j * TAGS + TSTOP];
    float mc = (lane < TAGS) ? cstop : -INFINITY;
    #pragma unroll
    for (int off = 32; off; off >>= 1) mc = fmaxf(mc, __shfl_xor(mc, off));
    float t = (lane < TAGS) ? P * fexp2((cstop - mc) * LOG2E) : 0.f;
    #pragma unroll
    for (int off = 32; off; off >>= 1) t += __shfl_xor(t, off);
    double fwd = ((double)M2 + (double)flog2(t)) * LN2d + (double)mc;

    float g = 0.f;
    for (int l = lane; l < len; l += 64) {
        int tt = tg[l];
        int pv = (l == 0) ? TSTART : tg[l - 1];
        g += flog2(le[l * TAGS + tt]) * LN2f + Tm[pv * TAGS + tt];
    }
    #pragma unroll
    for (int off = 32; off; off >>= 1) g += __shfl_xor(g, off);

    if (lane == 0) {
        double gold = (double)g + (double)Tm[tg[len - 1] * TAGS + TSTOP];
        partial[b] = fwd - gold;
    }
}

__global__ __launch_bounds__(256)
void crf_reduce_kernel(const double* __restrict__ partial, float* __restrict__ out, int B)
{
    __shared__ double sh[256];
    const int t = threadIdx.x;
    double acc = 0.0;
    for (int i = t; i < B; i += 256) acc += partial[i];
    sh[t] = acc;
    __syncthreads();
    for (int s = 128; s; s >>= 1) {
        if (t < s) sh[t] += sh[t + s];
        __syncthreads();
    }
    if (t == 0) out[0] = (float)sh[0];
}

extern "C" void kernel_launch(void* const* d_in, const int* in_sizes, int n_in,
                              void* d_out, int out_size, void* d_ws, size_t ws_size,
                              hipStream_t stream)
{
    const float* feats   = (const float*)d_in[0];
    const float* Tm      = (const float*)d_in[1];
    const int*   tags    = (const int*)d_in[2];
    const int*   lengths = (const int*)d_in[3];

    const int B = in_sizes[3];
    const int L = in_sizes[2] / B;

    double* partial = (double*)d_ws;

    if (L == 512 && ws_size >= (size_t)B * sizeof(double)) {
        crf_fused_kernel<<<B, 512, 0, stream>>>(feats, Tm, tags, lengths, partial, L);
        crf_reduce_kernel<<<1, 256, 0, stream>>>(partial, (float*)d_out, B);
    } else {
        crf_fwd_kernel<<<B, 64, 0, stream>>>(feats, Tm, tags, lengths, partial, B, L);
        crf_reduce_kernel<<<1, 256, 0, stream>>>(partial, (float*)d_out, B);
    }
}

// Round 10
// 29.686 us; speedup vs baseline: 1.2146x; 1.2146x over previous
//
#include <hip/hip_runtime.h>
#include <hip/hip_bf16.h>
#include <math.h>

#define TAGS   20
#define TSTART (TAGS - 2)
#define TSTOP  (TAGS - 1)

constexpr float  LOG2E = 1.4426950408889634f;
constexpr float  LN2f  = 0.6931471805599453f;
constexpr double LN2d  = 0.69314718055994530942;

typedef __attribute__((ext_vector_type(8))) short short8;
typedef __attribute__((ext_vector_type(4))) float f32x4;
union U4 { unsigned int u[4]; short8 v; };

// f32x2 -> packed bf16x2, round-half-up (+0x8000 then high halves via one
// v_perm_b32) — validated rounds 7/8, absmax 0.0. 3 VALU ops.
__device__ __forceinline__ unsigned int pk2(float lo, float hi) {
    unsigned int a = __float_as_uint(hi) + 0x8000u;
    unsigned int b = __float_as_uint(lo) + 0x8000u;
#if __has_builtin(__builtin_amdgcn_perm)
    return __builtin_amdgcn_perm(a, b, 0x07060302u);   // {a[31:16], b[31:16]}
#else
    return (a & 0xFFFF0000u) | (b >> 16);
#endif
}
#if __has_builtin(__builtin_amdgcn_exp2f)
__device__ __forceinline__ float fexp2(float x) { return __builtin_amdgcn_exp2f(x); }
#else
__device__ __forceinline__ float fexp2(float x) { return exp2f(x); }
#endif
#if __has_builtin(__builtin_amdgcn_logf)
__device__ __forceinline__ float flog2(float x) { return __builtin_amdgcn_logf(x); }
#else
__device__ __forceinline__ float flog2(float x) { return log2f(x); }
#endif
__device__ __forceinline__ float frcp(float x) { return __builtin_amdgcn_rcpf(x); }
__device__ __forceinline__ float bcast(float v, int srclane) {
    return __int_as_float(__builtin_amdgcn_readlane(__float_as_int(v), srclane));
}
// k-slot -> state-row permutation (split-half layout of gfx950 16x16x32),
// applied consistently to A and B (validated end-to-end: rounds 4/5/7/8).
__device__ __forceinline__ int rho(int k) {
    int g = k >> 3, i = k & 7;
    return (i < 4) ? (4 * g + i) : (16 + 4 * g + (i - 4));
}

// ========================== FUSED KERNEL ==================================
// One block = one batch. 8 waves; wave w owns chunks w and w+8 (32 steps
// each), each SPLIT into two 16-step sub-chains -> 4 interleaved chains per
// wave (8 chains/SIMD, half the serial depth of r7). After the loop each
// wave pair-combines its sub-chains in its own LDS slot (same-wave
// write-then-prod, r7-L4-validated), then the r7 4-level tree, final
// v0^T*G_total, LSE, gold.
__global__ __launch_bounds__(512)
void crf_fused_kernel(const float* __restrict__ feats,
                      const float* __restrict__ Tm,
                      const int*   __restrict__ tags,
                      const int*   __restrict__ lengths,
                      double*      __restrict__ partial,
                      int L)
{
    __shared__ float  smem[16 * 1024];   // 64 KB: ef staging; later tree slots (stride 1088)
    __shared__ float  sv[32];
    __shared__ int    EsX[8];
    __shared__ float  gred[8];
    __shared__ double fwd_sh;

    const int b    = blockIdx.x;
    const int tid  = threadIdx.x;
    const int w    = tid >> 6;
    const int lane = tid & 63;
    const int G    = lane >> 4, col = lane & 15;
    const int len  = lengths[b];

    // ---- stage ef = 2^(feat*log2e) for chunks w and w+8 (32x32, pads 0) ----
    // Wave w reads only its own staged chunks -> no barrier needed (r8-validated).
    #pragma unroll
    for (int s = 0; s < 2; ++s) {
        const int c = w + 8 * s;
        float* efc = smem + c * 1024;
        const float* fc = feats + ((size_t)b * L + (size_t)c * 32) * TAGS;
        for (int it = lane; it < 160; it += 64) {       // 160 float4 = 640 floats
            float4 v = reinterpret_cast<const float4*>(fc)[it];
            float vv[4] = {v.x, v.y, v.z, v.w};
            #pragma unroll
            for (int u = 0; u < 4; ++u) {
                int f = it * 4 + u;
                int t = f / TAGS, tag = f - t * TAGS;
                efc[t * 32 + tag] = fexp2(vv[u] * LOG2E);
            }
        }
        for (int q = lane; q < 32 * 12; q += 64) {
            int t = q / 12;
            efc[t * 32 + 20 + (q - t * 12)] = 0.f;
        }
    }

    // ---- shared A fragments from T: A_x[m][k] = 2^(T[16x+m][rho(k)]*log2e) ----
    U4 A0, A1;
    #pragma unroll
    for (int t = 0; t < 4; ++t) {
        int k0 = 8 * G + 2 * t;
        int r0 = rho(k0), r1 = rho(k0 + 1);
        int m1 = 16 + col;
        float a00 = (r0 < TAGS) ? fexp2(Tm[col * TAGS + r0] * LOG2E) : 0.f;
        float a01 = (r1 < TAGS) ? fexp2(Tm[col * TAGS + r1] * LOG2E) : 0.f;
        float a10 = (m1 < TAGS && r0 < TAGS) ? fexp2(Tm[m1 * TAGS + r0] * LOG2E) : 0.f;
        float a11 = (m1 < TAGS && r1 < TAGS) ? fexp2(Tm[m1 * TAGS + r1] * LOG2E) : 0.f;
        A0.u[t] = pk2(a00, a01);
        A1.u[t] = pk2(a10, a11);
    }

    auto step = [&](f32x4& C00, f32x4& C01, f32x4& C10, f32x4& C11,
                    const float* efc, int t) {
        float4 e0 = *reinterpret_cast<const float4*>(&efc[t * 32 + 4 * G]);
        float4 e1 = *reinterpret_cast<const float4*>(&efc[t * 32 + 16 + 4 * G]);
        U4 B0, B1;
        B0.u[0] = pk2(C00[0] * e0.x, C00[1] * e0.y);
        B0.u[1] = pk2(C00[2] * e0.z, C00[3] * e0.w);
        B0.u[2] = pk2(C10[0] * e1.x, C10[1] * e1.y);
        B0.u[3] = pk2(C10[2] * e1.z, C10[3] * e1.w);
        B1.u[0] = pk2(C01[0] * e0.x, C01[1] * e0.y);
        B1.u[1] = pk2(C01[2] * e0.z, C01[3] * e0.w);
        B1.u[2] = pk2(C11[0] * e1.x, C11[1] * e1.y);
        B1.u[3] = pk2(C11[2] * e1.z, C11[3] * e1.w);
        f32x4 z = {0.f, 0.f, 0.f, 0.f};
        C00 = __builtin_amdgcn_mfma_f32_16x16x32_bf16(A0.v, B0.v, z, 0, 0, 0);
        C01 = __builtin_amdgcn_mfma_f32_16x16x32_bf16(A0.v, B1.v, z, 0, 0, 0);
        C10 = __builtin_amdgcn_mfma_f32_16x16x32_bf16(A1.v, B0.v, z, 0, 0, 0);
        C11 = __builtin_amdgcn_mfma_f32_16x16x32_bf16(A1.v, B1.v, z, 0, 0, 0);
    };
    auto strip = [&](f32x4& C00, f32x4& C01, f32x4& C10, f32x4& C11) -> int {
        float pr = C00[0] + C00[1] + C00[2] + C00[3] + C10[0] + C10[1] + C10[2] + C10[3];
        int pb = __builtin_amdgcn_readfirstlane(__float_as_int(pr)); // col0 sum, >0 always
        int ex = ((pb >> 23) & 0xFF) - 127;
        float s = __uint_as_float((unsigned)(127 - ex) << 23);       // 2^-ex
        #pragma unroll
        for (int j = 0; j < 4; ++j) { C00[j] *= s; C01[j] *= s; C10[j] *= s; C11[j] *= s; }
        return ex;
    };
    auto xwrP = [&](float* Xs, const f32x4& C00, const f32x4& C01,
                    const f32x4& C10, const f32x4& C11) {
        #pragma unroll
        for (int j = 0; j < 4; ++j) {
            Xs[(4 * G + j) * 34 + col]           = C00[j];
            Xs[(4 * G + j) * 34 + col + 16]      = C01[j];
            Xs[(16 + 4 * G + j) * 34 + col]      = C10[j];
            Xs[(16 + 4 * G + j) * 34 + col + 16] = C11[j];
        }
    };
    auto prodP = [&](const float* Xs, f32x4& C00, f32x4& C01,
                     f32x4& C10, f32x4& C11) -> int {
        U4 Ax0, Ax1;
        #pragma unroll
        for (int t = 0; t < 4; ++t) {
            int r = rho(8 * G + 2 * t);                 // rho(k0), rho(k0+1) adjacent
            float2 x0 = *reinterpret_cast<const float2*>(&Xs[col * 34 + r]);
            float2 x1 = *reinterpret_cast<const float2*>(&Xs[(16 + col) * 34 + r]);
            Ax0.u[t] = pk2(x0.x, x0.y);
            Ax1.u[t] = pk2(x1.x, x1.y);
        }
        U4 B0, B1;
        B0.u[0] = pk2(C00[0], C00[1]);
        B0.u[1] = pk2(C00[2], C00[3]);
        B0.u[2] = pk2(C10[0], C10[1]);
        B0.u[3] = pk2(C10[2], C10[3]);
        B1.u[0] = pk2(C01[0], C01[1]);
        B1.u[1] = pk2(C01[2], C01[3]);
        B1.u[2] = pk2(C11[0], C11[1]);
        B1.u[3] = pk2(C11[2], C11[3]);
        f32x4 z = {0.f, 0.f, 0.f, 0.f};
        f32x4 n00 = __builtin_amdgcn_mfma_f32_16x16x32_bf16(Ax0.v, B0.v, z, 0, 0, 0);
        f32x4 n01 = __builtin_amdgcn_mfma_f32_16x16x32_bf16(Ax0.v, B1.v, z, 0, 0, 0);
        f32x4 n10 = __builtin_amdgcn_mfma_f32_16x16x32_bf16(Ax1.v, B0.v, z, 0, 0, 0);
        f32x4 n11 = __builtin_amdgcn_mfma_f32_16x16x32_bf16(Ax1.v, B1.v, z, 0, 0, 0);
        C00 = n00; C01 = n01; C10 = n10; C11 = n11;
        return strip(C00, C01, C10, C11);
    };
    auto xwr = [&](int slot, const f32x4& C00, const f32x4& C01,
                   const f32x4& C10, const f32x4& C11, int E) {
        xwrP(smem + slot * 1088, C00, C01, C10, C11);
        if (lane == 0) EsX[slot] = E;
    };
    auto prod = [&](int slot, f32x4& C00, f32x4& C01, f32x4& C10, f32x4& C11) -> int {
        return prodP(smem + slot * 1088, C00, C01, C10, C11);
    };

    // ---- 4 interleaved 16-step sub-chains ----
    // chunk w  = [lo0..hi0]·[lo1..hi1]; chunk w+8 = [lo2..hi2]·[lo3..hi3]
    f32x4 C0_00, C0_01, C0_10, C0_11, C1_00, C1_01, C1_10, C1_11;
    f32x4 C2_00, C2_01, C2_10, C2_11, C3_00, C3_01, C3_10, C3_11;
    #pragma unroll
    for (int j = 0; j < 4; ++j) {
        float d = (4 * G + j == col) ? 1.f : 0.f;       // I (pad diag harmless)
        C0_00[j] = d; C0_11[j] = d; C0_01[j] = 0.f; C0_10[j] = 0.f;
        C1_00[j] = d; C1_11[j] = d; C1_01[j] = 0.f; C1_10[j] = 0.f;
        C2_00[j] = d; C2_11[j] = d; C2_01[j] = 0.f; C2_10[j] = 0.f;
        C3_00[j] = d; C3_11[j] = d; C3_01[j] = 0.f; C3_10[j] = 0.f;
    }
    int E0 = 0, E1 = 0, E2 = 0, E3 = 0;

    const int baseA = w * 32, baseB = (w + 8) * 32;
    const int lo0 = (w == 0) ? 1 : baseA;
    const int hi0 = min(baseA + 15, len - 1);
    const int lo1 = baseA + 16;
    const int hi1 = min(baseA + 31, len - 1);
    const int lo2 = baseB;
    const int hi2 = min(baseB + 15, len - 1);
    const int lo3 = baseB + 16;
    const int hi3 = min(baseB + 31, len - 1);
    int n0 = max(hi0 - lo0 + 1, 0), n1 = max(hi1 - lo1 + 1, 0);
    int n2 = max(hi2 - lo2 + 1, 0), n3 = max(hi3 - lo3 + 1, 0);
    const int nmax = max(max(n0, n1), max(n2, n3));
    const float* efA = smem + w * 1024;
    const float* efB = smem + (w + 8) * 1024;

    int l0 = hi0, l1 = hi1, l2 = hi2, l3 = hi3;
    for (int i = 0; i < nmax; ++i) {
        if (i < n0) { step(C0_00, C0_01, C0_10, C0_11, efA, l0 - baseA); --l0; }
        if (i < n1) { step(C1_00, C1_01, C1_10, C1_11, efA, l1 - baseA); --l1; }
        if (i < n2) { step(C2_00, C2_01, C2_10, C2_11, efB, l2 - baseB); --l2; }
        if (i < n3) { step(C3_00, C3_01, C3_10, C3_11, efB, l3 - baseB); --l3; }
        if ((i & 3) == 3) {
            E0 += strip(C0_00, C0_01, C0_10, C0_11);
            E1 += strip(C1_00, C1_01, C1_10, C1_11);
            E2 += strip(C2_00, C2_01, C2_10, C2_11);
            E3 += strip(C3_00, C3_01, C3_10, C3_11);
        }
    }
    __syncthreads();   // ef dead everywhere; per-wave slots may overlap other waves' ef

    // ---- within-wave pair-combine: G_chunk = X(sub_lo) * C(sub_hi) ----
    float* myslot = smem + w * 1088;
    xwrP(myslot, C0_00, C0_01, C0_10, C0_11);
    int aE = E0 + E1 + prodP(myslot, C1_00, C1_01, C1_10, C1_11);  // C1 = G_w
    xwrP(myslot, C2_00, C2_01, C2_10, C2_11);
    int bE = E2 + E3 + prodP(myslot, C3_00, C3_01, C3_10, C3_11);  // C3 = G_{w+8}
    __syncthreads();   // slots reused by the tree

    // ---- tree level 1: P_p = G_{2p} * G_{2p+1} ----
    if ((w & 1) == 0) {
        xwr(w / 2,     C1_00, C1_01, C1_10, C1_11, aE);
        xwr(w / 2 + 4, C3_00, C3_01, C3_10, C3_11, bE);
    }
    __syncthreads();
    if (w & 1) {
        int pA = (w - 1) / 2;
        aE += EsX[pA]     + prod(pA,     C1_00, C1_01, C1_10, C1_11);
        bE += EsX[pA + 4] + prod(pA + 4, C3_00, C3_01, C3_10, C3_11);
    }
    __syncthreads();
    // ---- level 2 ----
    if (w == 1 || w == 5) {
        xwr((w - 1) / 4,     C1_00, C1_01, C1_10, C1_11, aE);
        xwr((w - 1) / 4 + 2, C3_00, C3_01, C3_10, C3_11, bE);
    }
    __syncthreads();
    if (w == 3 || w == 7) {
        int q = (w - 3) / 4;
        aE += EsX[q]     + prod(q,     C1_00, C1_01, C1_10, C1_11);
        bE += EsX[q + 2] + prod(q + 2, C3_00, C3_01, C3_10, C3_11);
    }
    __syncthreads();
    // ---- level 3 ----
    if (w == 3) {
        xwr(0, C1_00, C1_01, C1_10, C1_11, aE);
        xwr(1, C3_00, C3_01, C3_10, C3_11, bE);
    }
    __syncthreads();
    if (w == 7) {
        aE += EsX[0] + prod(0, C1_00, C1_01, C1_10, C1_11);
        bE += EsX[1] + prod(1, C3_00, C3_01, C3_10, C3_11);
    }
    __syncthreads();
    // ---- level 4 (same wave) ----
    if (w == 7) {
        xwr(0, C1_00, C1_01, C1_10, C1_11, aE);
        int ex = prod(0, C3_00, C3_01, C3_10, C3_11);   // G_total = R_0 * R_1
        int fE = aE + bE + ex;
        float* Gt = smem;                                // col-major: Gt[n*34 + r]
        #pragma unroll
        for (int j = 0; j < 4; ++j) {
            Gt[col * 34 + 4 * G + j]             = C3_00[j];
            Gt[col * 34 + 16 + 4 * G + j]        = C3_10[j];
            Gt[(col + 16) * 34 + 4 * G + j]      = C3_01[j];
            Gt[(col + 16) * 34 + 16 + 4 * G + j] = C3_11[j];
        }
        if (lane == 0) EsX[0] = fE;
    }
    __syncthreads();

    // ---- final: part^T = v0^T G_total ; LSE with T[:,STOP] (max-subtracted;
    //      the STOP column is -10000 everywhere!) ----
    if (w == 0) {
        const int n2_ = lane & 31;
        float p = (n2_ < TAGS) ? (feats[(size_t)b * L * TAGS + n2_] + Tm[TSTART * TAGS + n2_]) * LOG2E
                               : -1e30f;
        float mx = p;
        #pragma unroll
        for (int off = 32; off; off >>= 1) mx = fmaxf(mx, __shfl_xor(mx, off));
        float v = (n2_ < TAGS) ? fexp2(p - mx) : 0.f;
        if (lane < 32) sv[lane] = v;                     // same-wave DS ordering
        const float* Gt = smem;
        float vn = 0.f;
        #pragma unroll
        for (int r = 0; r < 32; r += 2) {
            float2 g2 = *reinterpret_cast<const float2*>(&Gt[n2_ * 34 + r]);
            vn = fmaf(sv[r], g2.x, vn);
            vn = fmaf(sv[r + 1], g2.y, vn);
        }
        float cstop = Tm[n2_ * TAGS + TSTOP];
        float mc = (n2_ < TAGS) ? cstop : -INFINITY;
        #pragma unroll
        for (int off = 32; off; off >>= 1) mc = fmaxf(mc, __shfl_xor(mc, off));
        float ts = (lane < 32 && n2_ < TAGS) ? vn * fexp2((cstop - mc) * LOG2E) : 0.f;
        #pragma unroll
        for (int off = 32; off; off >>= 1) ts += __shfl_xor(ts, off);
        if (lane == 0)
            fwd_sh = ((double)mx + (double)EsX[0] + (double)flog2(ts)) * LN2d + (double)mc;
    }

    // ---- gold path score (all 512 threads) ----
    float g = 0.f;
    for (int l = tid; l < len; l += 512) {
        int tt = tags[(size_t)b * L + l];
        int pv = (l == 0) ? TSTART : tags[(size_t)b * L + l - 1];
        g += feats[((size_t)b * L + l) * TAGS + tt] + Tm[pv * TAGS + tt];
    }
    #pragma unroll
    for (int off = 32; off; off >>= 1) g += __shfl_xor(g, off);
    if (lane == 0) gred[w] = g;
    __syncthreads();

    if (tid == 0) {
        float gs = gred[0] + gred[1] + gred[2] + gred[3]
                 + gred[4] + gred[5] + gred[6] + gred[7];
        double gold = (double)gs + (double)Tm[tags[(size_t)b * L + len - 1] * TAGS + TSTOP];
        partial[b] = fwd_sh - gold;
    }
}

// ==================== FALLBACK (round-2 serial kernel) ====================
__global__ __launch_bounds__(64)
void crf_fwd_kernel(const float* __restrict__ feats,
                    const float* __restrict__ Tm,
                    const int*   __restrict__ tags,
                    const int*   __restrict__ lengths,
                    double*      __restrict__ partial,
                    int B, int L)
{
    __shared__ float le[512 * TAGS];
    const int b    = blockIdx.x;
    const int lane = threadIdx.x;
    const int j    = (lane < TAGS) ? lane : 0;
    const float* fb  = feats + (size_t)b * L * TAGS;
    const int*   tg  = tags  + (size_t)b * L;
    const int    len = lengths[b];

    const int nv4 = (L * TAGS) >> 2;
    for (int it = lane; it < nv4; it += 64) {
        float4 v = reinterpret_cast<const float4*>(fb)[it];
        float4 e;
        e.x = fexp2(v.x * LOG2E); e.y = fexp2(v.y * LOG2E);
        e.z = fexp2(v.z * LOG2E); e.w = fexp2(v.w * LOG2E);
        reinterpret_cast<float4*>(le)[it] = e;
    }
    __syncthreads();

    float ET[TAGS];
    #pragma unroll
    for (int i = 0; i < TAGS; ++i) ET[i] = fexp2(Tm[i * TAGS + j] * LOG2E);

    float w0   = flog2(le[j]) + Tm[TSTART * TAGS + j] * LOG2E;
    float base = bcast(w0, 0);
    float P    = fexp2(w0 - base);
    float M2   = base;
    float Pa[TAGS];
    #pragma unroll
    for (int i = 0; i < TAGS; ++i) Pa[i] = bcast(P, i);
    const float* leb = le + j;

    auto STEP = [&](int l, float efv, float rsv, bool scaled) {
        float s0 = 0.f, s1 = 0.f, s2 = 0.f, s3 = 0.f;
        #pragma unroll
        for (int i = 0; i < TAGS; i += 4) {
            s0 = fmaf(ET[i + 0], Pa[i + 0], s0);
            s1 = fmaf(ET[i + 1], Pa[i + 1], s1);
            s2 = fmaf(ET[i + 2], Pa[i + 2], s2);
            s3 = fmaf(ET[i + 3], Pa[i + 3], s3);
        }
        float s   = (s0 + s1) + (s2 + s3);
        float cur = s * efv;
        float pn  = (l < len) ? cur : P;
        P = scaled ? pn * rsv : pn;
        #pragma unroll
        for (int i = 0; i < TAGS; ++i) Pa[i] = bcast(P, i);
    };

    float efb[4];
    #pragma unroll
    for (int k = 0; k < 4; ++k) { int ln = 1 + k; ln = (ln < L) ? ln : (L - 1); efb[k] = leb[ln * TAGS]; }

    float rs = 1.0f, lg0 = 0.0f;
    int l0 = 1;
    for (; l0 + 3 < L; l0 += 4) {
        if (l0 >= len) break;
        float efn[4];
        #pragma unroll
        for (int k = 0; k < 4; ++k) { int ln = l0 + 4 + k; ln = (ln < L) ? ln : (L - 1); efn[k] = leb[ln * TAGS]; }
        M2 += lg0;
        STEP(l0 + 0, efb[0], rs, true);
        STEP(l0 + 1, efb[1], 1.f, false);
        STEP(l0 + 2, efb[2], 1.f, false);
        STEP(l0 + 3, efb[3], 1.f, false);
        float p0 = Pa[0];
        rs = frcp(p0); lg0 = flog2(p0);
        #pragma unroll
        for (int k = 0; k < 4; ++k) efb[k] = efn[k];
    }
    if (l0 < len) {
        int rem = L - l0;
        M2 += lg0;
        if (rem > 0) STEP(l0 + 0, efb[0], rs, true);
        if (rem > 1) STEP(l0 + 1, efb[1], 1.f, false);
        if (rem > 2) STEP(l0 + 2, efb[2], 1.f, false);
        if (rem > 3) STEP(l0 + 3, efb[3], 1.f, false);
    }

    float cstop = Tm[j * TAGS + TSTOP];
    float mc = (lane < TAGS) ? cstop : -INFINITY;
    #pragma unroll
    for (int off = 32; off; off >>= 1) mc = fmaxf(mc, __shfl_xor(mc, off));
    float t = (lane < TAGS) ? P * fexp2((cstop - mc) * LOG2E) : 0.f;
    #pragma unroll
    for (int off = 32; off; off >>= 1) t += __shfl_xor(t, off);
    double fwd = ((double)M2 + (double)flog2(t)) * LN2d + (double)mc;

    float g = 0.f;
    for (int l = lane; l < len; l += 64) {
        int tt = tg[l];
        int pv = (l == 0) ? TSTART : tg[l - 1];
        g += flog2(le[l * TAGS + tt]) * LN2f + Tm[pv * TAGS + tt];
    }
    #pragma unroll
    for (int off = 32; off; off >>= 1) g += __shfl_xor(g, off);

    if (lane == 0) {
        double gold = (double)g + (double)Tm[tg[len - 1] * TAGS + TSTOP];
        partial[b] = fwd - gold;
    }
}

__global__ __launch_bounds__(256)
void crf_reduce_kernel(const double* __restrict__ partial, float* __restrict__ out, int B)
{
    __shared__ double sh[256];
    const int t = threadIdx.x;
    double acc = 0.0;
    for (int i = t; i < B; i += 256) acc += partial[i];
    sh[t] = acc;
    __syncthreads();
    for (int s = 128; s; s >>= 1) {
        if (t < s) sh[t] += sh[t + s];
        __syncthreads();
    }
    if (t == 0) out[0] = (float)sh[0];
}

extern "C" void kernel_launch(void* const* d_in, const int* in_sizes, int n_in,
                              void* d_out, int out_size, void* d_ws, size_t ws_size,
                              hipStream_t stream)
{
    const float* feats   = (const float*)d_in[0];
    const float* Tm      = (const float*)d_in[1];
    const int*   tags    = (const int*)d_in[2];
    const int*   lengths = (const int*)d_in[3];

    const int B = in_sizes[3];
    const int L = in_sizes[2] / B;

    double* partial = (double*)d_ws;

    if (L == 512 && ws_size >= (size_t)B * sizeof(double)) {
        crf_fused_kernel<<<B, 512, 0, stream>>>(feats, Tm, tags, lengths, partial, L);
        crf_reduce_kernel<<<1, 256, 0, stream>>>(partial, (float*)d_out, B);
    } else {
        crf_fwd_kernel<<<B, 64, 0, stream>>>(feats, Tm, tags, lengths, partial, B, L);
        crf_reduce_kernel<<<1, 256, 0, stream>>>(partial, (float*)d_out, B);
    }
}

// Round 11
// 29.584 us; speedup vs baseline: 1.2188x; 1.0034x over previous
//
#include <hip/hip_runtime.h>
#include <hip/hip_bf16.h>
#include <math.h>

#define TAGS   20
#define TSTART (TAGS - 2)
#define TSTOP  (TAGS - 1)

constexpr float  LOG2E = 1.4426950408889634f;
constexpr float  LN2f  = 0.6931471805599453f;
constexpr double LN2d  = 0.69314718055994530942;

typedef __attribute__((ext_vector_type(8)))  short short8;
typedef __attribute__((ext_vector_type(16))) float f32x16;
union U4 { unsigned int u[4]; short8 v; };

// f32x2 -> packed bf16x2, round-half-up (+0x8000 then high halves via one
// v_perm_b32) — validated rounds 7/8/10, absmax 0.0. 3 VALU ops.
__device__ __forceinline__ unsigned int pk2(float lo, float hi) {
    unsigned int a = __float_as_uint(hi) + 0x8000u;
    unsigned int b = __float_as_uint(lo) + 0x8000u;
#if __has_builtin(__builtin_amdgcn_perm)
    return __builtin_amdgcn_perm(a, b, 0x07060302u);   // {a[31:16], b[31:16]}
#else
    return (a & 0xFFFF0000u) | (b >> 16);
#endif
}
#if __has_builtin(__builtin_amdgcn_exp2f)
__device__ __forceinline__ float fexp2(float x) { return __builtin_amdgcn_exp2f(x); }
#else
__device__ __forceinline__ float fexp2(float x) { return exp2f(x); }
#endif
#if __has_builtin(__builtin_amdgcn_logf)
__device__ __forceinline__ float flog2(float x) { return __builtin_amdgcn_logf(x); }
#else
__device__ __forceinline__ float flog2(float x) { return log2f(x); }
#endif
__device__ __forceinline__ float frcp(float x) { return __builtin_amdgcn_rcpf(x); }
__device__ __forceinline__ float bcast(float v, int srclane) {
    return __int_as_float(__builtin_amdgcn_readlane(__float_as_int(v), srclane));
}

// 32x32x16 split-half A/B k-slot base for elem-pair p (pairs 0,1 -> k=4h+2p;
// pairs 2,3 -> k=8+4h+2(p-2)). Same doubling rule whose 16x16x32 instance
// (rho) was hardware-validated in rounds 4-10.
__device__ __forceinline__ int kbase(int p, int h) {
    return (p < 2) ? (4 * h + 2 * p) : (8 + 4 * h + 2 * (p - 2));
}
// 32x32 C/D row for reg j, lane-half h (guide-verified m74/m101)
__device__ __forceinline__ int crow(int j, int h) {
    return (j & 3) + 8 * (j >> 2) + 4 * h;
}

// ========================== FUSED KERNEL ==================================
// One block = one batch. 8 waves; wave w owns chunks w and w+8 (32 steps
// each, interleaved). Step = 2x mfma_f32_32x32x16_bf16 (K=32 via C-in
// chaining); C/D regs feed next-step B operands with zero permutation.
// A = 2^T constant. Strip every 4 steps. 4-level MFMA tree in LDS, final
// v0^T*G_total, LSE, gold — structure identical to round 7.
__global__ __launch_bounds__(512)
void crf_fused_kernel(const float* __restrict__ feats,
                      const float* __restrict__ Tm,
                      const int*   __restrict__ tags,
                      const int*   __restrict__ lengths,
                      double*      __restrict__ partial,
                      int L)
{
    __shared__ float  smem[16 * 1024];   // 64 KB: ef staging; later tree slots (stride 1088)
    __shared__ float  sv[32];
    __shared__ int    EsX[8];
    __shared__ float  gred[8];
    __shared__ double fwd_sh;

    const int b    = blockIdx.x;
    const int tid  = threadIdx.x;
    const int w    = tid >> 6;
    const int lane = tid & 63;
    const int m    = lane & 31;          // output row (A) / column (C,B)
    const int h    = lane >> 5;          // lane half
    const int len  = lengths[b];

    // ---- stage ef = 2^(feat*log2e) for chunks w and w+8 (32x32, pads 0) ----
    #pragma unroll
    for (int s = 0; s < 2; ++s) {
        const int c = w + 8 * s;
        float* efc = smem + c * 1024;
        const float* fc = feats + ((size_t)b * L + (size_t)c * 32) * TAGS;
        for (int it = lane; it < 160; it += 64) {       // 160 float4 = 640 floats
            float4 v = reinterpret_cast<const float4*>(fc)[it];
            float vv[4] = {v.x, v.y, v.z, v.w};
            #pragma unroll
            for (int u = 0; u < 4; ++u) {
                int f = it * 4 + u;
                int t = f / TAGS, tag = f - t * TAGS;
                efc[t * 32 + tag] = fexp2(vv[u] * LOG2E);
            }
        }
        for (int q = lane; q < 32 * 12; q += 64) {
            int t = q / 12;
            efc[t * 32 + 20 + (q - t * 12)] = 0.f;
        }
    }

    // ---- constant A fragments: A1 = 2^T[:,k<16], A2 = 2^T[:,k>=16] ----
    U4 A1g, A2g;
    #pragma unroll
    for (int p = 0; p < 4; ++p) {
        int r = kbase(p, h);
        float a0 = (m < TAGS && r     < TAGS) ? fexp2(Tm[m * TAGS + r]      * LOG2E) : 0.f;
        float a1 = (m < TAGS && r + 1 < TAGS) ? fexp2(Tm[m * TAGS + r + 1]  * LOG2E) : 0.f;
        float b0 = (m < TAGS && r + 16 < TAGS) ? fexp2(Tm[m * TAGS + r + 16] * LOG2E) : 0.f;
        float b1 = (m < TAGS && r + 17 < TAGS) ? fexp2(Tm[m * TAGS + r + 17] * LOG2E) : 0.f;
        A1g.u[p] = pk2(a0, a1);
        A2g.u[p] = pk2(b0, b1);
    }

    // step: C <- ET * (D_l * C) via 2 MFMAs (C-in chained)
    auto step = [&](f32x16& C, const float* efc, int t) {
        float4 ea = *reinterpret_cast<const float4*>(&efc[t * 32 + 4 * h]);
        float4 eb = *reinterpret_cast<const float4*>(&efc[t * 32 + 8 + 4 * h]);
        float4 ec = *reinterpret_cast<const float4*>(&efc[t * 32 + 16 + 4 * h]);
        float4 ed = *reinterpret_cast<const float4*>(&efc[t * 32 + 24 + 4 * h]);
        U4 B1, B2;
        B1.u[0] = pk2(C[0]  * ea.x, C[1]  * ea.y);
        B1.u[1] = pk2(C[2]  * ea.z, C[3]  * ea.w);
        B1.u[2] = pk2(C[4]  * eb.x, C[5]  * eb.y);
        B1.u[3] = pk2(C[6]  * eb.z, C[7]  * eb.w);
        B2.u[0] = pk2(C[8]  * ec.x, C[9]  * ec.y);
        B2.u[1] = pk2(C[10] * ec.z, C[11] * ec.w);
        B2.u[2] = pk2(C[12] * ed.x, C[13] * ed.y);
        B2.u[3] = pk2(C[14] * ed.z, C[15] * ed.w);
        f32x16 z = {0.f,0.f,0.f,0.f,0.f,0.f,0.f,0.f,0.f,0.f,0.f,0.f,0.f,0.f,0.f,0.f};
        f32x16 t1 = __builtin_amdgcn_mfma_f32_32x32x16_bf16(A1g.v, B1.v, z,  0, 0, 0);
        C         = __builtin_amdgcn_mfma_f32_32x32x16_bf16(A2g.v, B2.v, t1, 0, 0, 0);
    };
    auto strip = [&](f32x16& C) -> int {
        float pr = ((C[0]+C[1])+(C[2]+C[3])) + ((C[4]+C[5])+(C[6]+C[7]))
                 + ((C[8]+C[9])+(C[10]+C[11])) + ((C[12]+C[13])+(C[14]+C[15]));
        int pb = __builtin_amdgcn_readfirstlane(__float_as_int(pr)); // col0 half-sum, >0
        int ex = ((pb >> 23) & 0xFF) - 127;
        float s = __uint_as_float((unsigned)(127 - ex) << 23);       // 2^-ex
        #pragma unroll
        for (int j = 0; j < 16; ++j) C[j] *= s;
        return ex;
    };
    auto xwrP = [&](float* Xs, const f32x16& C) {       // row-major, stride 34
        #pragma unroll
        for (int j = 0; j < 16; ++j) Xs[crow(j, h) * 34 + m] = C[j];
    };
    auto prodP = [&](const float* Xs, f32x16& C) -> int {  // C <- X * C
        U4 Ax1, Ax2;
        #pragma unroll
        for (int p = 0; p < 4; ++p) {
            int r = kbase(p, h);
            float2 x1 = *reinterpret_cast<const float2*>(&Xs[m * 34 + r]);
            float2 x2 = *reinterpret_cast<const float2*>(&Xs[m * 34 + r + 16]);
            Ax1.u[p] = pk2(x1.x, x1.y);
            Ax2.u[p] = pk2(x2.x, x2.y);
        }
        U4 B1, B2;
        B1.u[0] = pk2(C[0],  C[1]);
        B1.u[1] = pk2(C[2],  C[3]);
        B1.u[2] = pk2(C[4],  C[5]);
        B1.u[3] = pk2(C[6],  C[7]);
        B2.u[0] = pk2(C[8],  C[9]);
        B2.u[1] = pk2(C[10], C[11]);
        B2.u[2] = pk2(C[12], C[13]);
        B2.u[3] = pk2(C[14], C[15]);
        f32x16 z = {0.f,0.f,0.f,0.f,0.f,0.f,0.f,0.f,0.f,0.f,0.f,0.f,0.f,0.f,0.f,0.f};
        f32x16 t1 = __builtin_amdgcn_mfma_f32_32x32x16_bf16(Ax1.v, B1.v, z,  0, 0, 0);
        C         = __builtin_amdgcn_mfma_f32_32x32x16_bf16(Ax2.v, B2.v, t1, 0, 0, 0);
        return strip(C);
    };
    auto xwr = [&](int slot, const f32x16& C, int E) {
        xwrP(smem + slot * 1088, C);
        if (lane == 0) EsX[slot] = E;
    };
    auto prod = [&](int slot, f32x16& C) -> int {
        return prodP(smem + slot * 1088, C);
    };

    // ---- two interleaved 32-step chunk products (chains: chunk w, chunk w+8) ----
    f32x16 Ca, Cb;
    #pragma unroll
    for (int j = 0; j < 16; ++j) {
        float d = (crow(j, h) == m) ? 1.f : 0.f;        // I (pad diag harmless)
        Ca[j] = d; Cb[j] = d;
    }
    int aE = 0, bE = 0;

    const int cB  = w + 8;
    const int loA = (w == 0) ? 1 : w * 32;
    const int hiA = min(w * 32 + 31, len - 1);
    const int loB = cB * 32;
    const int hiB = min(cB * 32 + 31, len - 1);
    int nA = hiA - loA + 1; if (nA < 0) nA = 0;
    int nB = hiB - loB + 1; if (nB < 0) nB = 0;
    const int n = max(nA, nB);
    const float* efA = smem + w * 1024;
    const float* efB = smem + cB * 1024;

    int lA = hiA, lB = hiB;
    for (int i = 0; i < n; ++i) {
        if (i < nA) { step(Ca, efA, lA - w * 32);  --lA; }
        if (i < nB) { step(Cb, efB, lB - cB * 32); --lB; }
        if ((i & 3) == 3) {
            aE += strip(Ca);
            bE += strip(Cb);
        }
    }
    __syncthreads();   // ef region dead; reuse smem as tree slots

    // ---- tree level 1: P_p = G_{2p} * G_{2p+1} ----
    if ((w & 1) == 0) {
        xwr(w / 2,     Ca, aE);
        xwr(w / 2 + 4, Cb, bE);
    }
    __syncthreads();
    if (w & 1) {
        int pA = (w - 1) / 2;
        aE += EsX[pA]     + prod(pA,     Ca);
        bE += EsX[pA + 4] + prod(pA + 4, Cb);
    }
    __syncthreads();
    // ---- level 2 ----
    if (w == 1 || w == 5) {
        xwr((w - 1) / 4,     Ca, aE);
        xwr((w - 1) / 4 + 2, Cb, bE);
    }
    __syncthreads();
    if (w == 3 || w == 7) {
        int q = (w - 3) / 4;
        aE += EsX[q]     + prod(q,     Ca);
        bE += EsX[q + 2] + prod(q + 2, Cb);
    }
    __syncthreads();
    // ---- level 3 ----
    if (w == 3) {
        xwr(0, Ca, aE);
        xwr(1, Cb, bE);
    }
    __syncthreads();
    if (w == 7) {
        aE += EsX[0] + prod(0, Ca);
        bE += EsX[1] + prod(1, Cb);
    }
    __syncthreads();
    // ---- level 4 (same wave: no barrier between write & read) ----
    if (w == 7) {
        xwr(0, Ca, aE);
        int ex = prodP(smem, Cb);                       // G_total = R_0 * R_1
        int fE = aE + bE + ex;
        float* Gt = smem;                                // Gt[n*34 + r] = G[r][n]
        #pragma unroll
        for (int j = 0; j < 16; ++j) Gt[m * 34 + crow(j, h)] = Cb[j];
        if (lane == 0) EsX[0] = fE;
    }
    __syncthreads();

    // ---- final: part^T = v0^T G_total ; LSE with T[:,STOP] (max-subtracted;
    //      the STOP column is -10000 everywhere!) ----
    if (w == 0) {
        const int n2 = lane & 31;
        float p = (n2 < TAGS) ? (feats[(size_t)b * L * TAGS + n2] + Tm[TSTART * TAGS + n2]) * LOG2E
                              : -1e30f;
        float mx = p;
        #pragma unroll
        for (int off = 32; off; off >>= 1) mx = fmaxf(mx, __shfl_xor(mx, off));
        float v = (n2 < TAGS) ? fexp2(p - mx) : 0.f;
        if (lane < 32) sv[lane] = v;                  // same-wave DS ordering
        const float* Gt = smem;
        float vn = 0.f;
        #pragma unroll
        for (int r = 0; r < 32; r += 2) {
            float2 g2 = *reinterpret_cast<const float2*>(&Gt[n2 * 34 + r]);
            vn = fmaf(sv[r], g2.x, vn);
            vn = fmaf(sv[r + 1], g2.y, vn);
        }
        float cstop = Tm[n2 * TAGS + TSTOP];
        float mc = (n2 < TAGS) ? cstop : -INFINITY;
        #pragma unroll
        for (int off = 32; off; off >>= 1) mc = fmaxf(mc, __shfl_xor(mc, off));
        float ts = (lane < 32 && n2 < TAGS) ? vn * fexp2((cstop - mc) * LOG2E) : 0.f;
        #pragma unroll
        for (int off = 32; off; off >>= 1) ts += __shfl_xor(ts, off);
        if (lane == 0)
            fwd_sh = ((double)mx + (double)EsX[0] + (double)flog2(ts)) * LN2d + (double)mc;
    }

    // ---- gold path score (all 512 threads) ----
    float g = 0.f;
    for (int l = tid; l < len; l += 512) {
        int tt = tags[(size_t)b * L + l];
        int pv = (l == 0) ? TSTART : tags[(size_t)b * L + l - 1];
        g += feats[((size_t)b * L + l) * TAGS + tt] + Tm[pv * TAGS + tt];
    }
    #pragma unroll
    for (int off = 32; off; off >>= 1) g += __shfl_xor(g, off);
    if (lane == 0) gred[w] = g;
    __syncthreads();

    if (tid == 0) {
        float gs = gred[0] + gred[1] + gred[2] + gred[3]
                 + gred[4] + gred[5] + gred[6] + gred[7];
        double gold = (double)gs + (double)Tm[tags[(size_t)b * L + len - 1] * TAGS + TSTOP];
        partial[b] = fwd_sh - gold;
    }
}

// ==================== FALLBACK (round-2 serial kernel) ====================
__global__ __launch_bounds__(64)
void crf_fwd_kernel(const float* __restrict__ feats,
                    const float* __restrict__ Tm,
                    const int*   __restrict__ tags,
                    const int*   __restrict__ lengths,
                    double*      __restrict__ partial,
                    int B, int L)
{
    __shared__ float le[512 * TAGS];
    const int b    = blockIdx.x;
    const int lane = threadIdx.x;
    const int j    = (lane < TAGS) ? lane : 0;
    const float* fb  = feats + (size_t)b * L * TAGS;
    const int*   tg  = tags  + (size_t)b * L;
    const int    len = lengths[b];

    const int nv4 = (L * TAGS) >> 2;
    for (int it = lane; it < nv4; it += 64) {
        float4 v = reinterpret_cast<const float4*>(fb)[it];
        float4 e;
        e.x = fexp2(v.x * LOG2E); e.y = fexp2(v.y * LOG2E);
        e.z = fexp2(v.z * LOG2E); e.w = fexp2(v.w * LOG2E);
        reinterpret_cast<float4*>(le)[it] = e;
    }
    __syncthreads();

    float ET[TAGS];
    #pragma unroll
    for (int i = 0; i < TAGS; ++i) ET[i] = fexp2(Tm[i * TAGS + j] * LOG2E);

    float w0   = flog2(le[j]) + Tm[TSTART * TAGS + j] * LOG2E;
    float base = bcast(w0, 0);
    float P    = fexp2(w0 - base);
    float M2   = base;
    float Pa[TAGS];
    #pragma unroll
    for (int i = 0; i < TAGS; ++i) Pa[i] = bcast(P, i);
    const float* leb = le + j;

    auto STEP = [&](int l, float efv, float rsv, bool scaled) {
        float s0 = 0.f, s1 = 0.f, s2 = 0.f, s3 = 0.f;
        #pragma unroll
        for (int i = 0; i < TAGS; i += 4) {
            s0 = fmaf(ET[i + 0], Pa[i + 0], s0);
            s1 = fmaf(ET[i + 1], Pa[i + 1], s1);
            s2 = fmaf(ET[i + 2], Pa[i + 2], s2);
            s3 = fmaf(ET[i + 3], Pa[i + 3], s3);
        }
        float s   = (s0 + s1) + (s2 + s3);
        float cur = s * efv;
        float pn  = (l < len) ? cur : P;
        P = scaled ? pn * rsv : pn;
        #pragma unroll
        for (int i = 0; i < TAGS; ++i) Pa[i] = bcast(P, i);
    };

    float efb[4];
    #pragma unroll
    for (int k = 0; k < 4; ++k) { int ln = 1 + k; ln = (ln < L) ? ln : (L - 1); efb[k] = leb[ln * TAGS]; }

    float rs = 1.0f, lg0 = 0.0f;
    int l0 = 1;
    for (; l0 + 3 < L; l0 += 4) {
        if (l0 >= len) break;
        float efn[4];
        #pragma unroll
        for (int k = 0; k < 4; ++k) { int ln = l0 + 4 + k; ln = (ln < L) ? ln : (L - 1); efn[k] = leb[ln * TAGS]; }
        M2 += lg0;
        STEP(l0 + 0, efb[0], rs, true);
        STEP(l0 + 1, efb[1], 1.f, false);
        STEP(l0 + 2, efb[2], 1.f, false);
        STEP(l0 + 3, efb[3], 1.f, false);
        float p0 = Pa[0];
        rs = frcp(p0); lg0 = flog2(p0);
        #pragma unroll
        for (int k = 0; k < 4; ++k) efb[k] = efn[k];
    }
    if (l0 < len) {
        int rem = L - l0;
        M2 += lg0;
        if (rem > 0) STEP(l0 + 0, efb[0], rs, true);
        if (rem > 1) STEP(l0 + 1, efb[1], 1.f, false);
        if (rem > 2) STEP(l0 + 2, efb[2], 1.f, false);
        if (rem > 3) STEP(l0 + 3, efb[3], 1.f, false);
    }

    float cstop = Tm[j * TAGS + TSTOP];
    float mc = (lane < TAGS) ? cstop : -INFINITY;
    #pragma unroll
    for (int off = 32; off; off >>= 1) mc = fmaxf(mc, __shfl_xor(mc, off));
    float t = (lane < TAGS) ? P * fexp2((cstop - mc) * LOG2E) : 0.f;
    #pragma unroll
    for (int off = 32; off; off >>= 1) t += __shfl_xor(t, off);
    double fwd = ((double)M2 + (double)flog2(t)) * LN2d + (double)mc;

    float g = 0.f;
    for (int l = lane; l < len; l += 64) {
        int tt = tg[l];
        int pv = (l == 0) ? TSTART : tg[l - 1];
        g += flog2(le[l * TAGS + tt]) * LN2f + Tm[pv * TAGS + tt];
    }
    #pragma unroll
    for (int off = 32; off; off >>= 1) g += __shfl_xor(g, off);

    if (lane == 0) {
        double gold = (double)g + (double)Tm[tg[len - 1] * TAGS + TSTOP];
        partial[b] = fwd - gold;
    }
}

__global__ __launch_bounds__(256)
void crf_reduce_kernel(const double* __restrict__ partial, float* __restrict__ out, int B)
{
    __shared__ double sh[256];
    const int t = threadIdx.x;
    double acc = 0.0;
    for (int i = t; i < B; i += 256) acc += partial[i];
    sh[t] = acc;
    __syncthreads();
    for (int s = 128; s; s >>= 1) {
        if (t < s) sh[t] += sh[t + s];
        __syncthreads();
    }
    if (t == 0) out[0] = (float)sh[0];
}

extern "C" void kernel_launch(void* const* d_in, const int* in_sizes, int n_in,
                              void* d_out, int out_size, void* d_ws, size_t ws_size,
                              hipStream_t stream)
{
    const float* feats   = (const float*)d_in[0];
    const float* Tm      = (const float*)d_in[1];
    const int*   tags    = (const int*)d_in[2];
    const int*   lengths = (const int*)d_in[3];

    const int B = in_sizes[3];
    const int L = in_sizes[2] / B;

    double* partial = (double*)d_ws;

    if (L == 512 && ws_size >= (size_t)B * sizeof(double)) {
        crf_fused_kernel<<<B, 512, 0, stream>>>(feats, Tm, tags, lengths, partial, L);
        crf_reduce_kernel<<<1, 256, 0, stream>>>(partial, (float*)d_out, B);
    } else {
        crf_fwd_kernel<<<B, 64, 0, stream>>>(feats, Tm, tags, lengths, partial, B, L);
        crf_reduce_kernel<<<1, 256, 0, stream>>>(partial, (float*)d_out, B);
    }
}